// Round 2
// baseline (588.112 us; speedup 1.0000x reference)
//
#include <hip/hip_runtime.h>

typedef float v2 __attribute__((ext_vector_type(2)));
typedef float v4 __attribute__((ext_vector_type(4)));

#define B_TOT 2048
#define T_STEPS 512
// D = 8, M = 2

// out layout (flat floats):
//   means: [B,T,8]    at 0
//   covs : [B,T,8,8]  at 8388608
//   Rs   : [B,T,2,2]  at 75497472
//   Hs   : [B,T,2,8]  at 79691776
#define OFF_COVS 8388608
#define OFF_RS   75497472
#define OFF_HS   79691776

static __device__ __forceinline__ v2 sp(float s) { v2 r; r.x = s; r.y = s; return r; }

__launch_bounds__(64, 1)
__global__ void kf_kernel(const float* __restrict__ input,
                          const float* __restrict__ mean0,
                          const float* __restrict__ cov0,
                          const float* __restrict__ Fm,
                          const float* __restrict__ Hm,
                          const float* __restrict__ Qm,
                          const float* __restrict__ Rm,
                          float* __restrict__ out)
{
    // LDS. Strides chosen for <=2-way bank aliasing (free). Block = 1 wave:
    // NO __syncthreads anywhere — intra-wave DS ops are in-order; compiler
    // alias analysis + lgkmcnt provide write->read ordering.
    __shared__ float xs[8 * 1024];      // staged input: 8 groups x (T*M)
    __shared__ float hps[8 * 28];       // [g*28 + m*10 + j]
    __shared__ float ws[8 * 84];        // [g*84 + d*10 + j]  (W column scatter)
    __shared__ float mean_s[8 * 12];    // [g*12 + j]

    const int lane = threadIdx.x;       // 0..63
    const int g = lane >> 3;            // group within block
    const int j = lane & 7;             // row index
    const int b0 = blockIdx.x * 8;
    const int b = b0 + g;

    // ---- stage this block's input rows (8 groups x 1024 floats, contiguous) ----
    {
        const v4* src = (const v4*)(input + (size_t)b0 * 1024);
        v4* dst = (v4*)xs;
        #pragma unroll
        for (int i = 0; i < 32; ++i)
            dst[i * 64 + lane] = src[i * 64 + lane];
    }

    // ---- replicated constants ----
    // Fcol2[f][d2] = { F[2*d2, f], F[2*d2+1, f] }  (serves X -> F*X and X*F^T)
    v2 Fcol2[8][4];
    #pragma unroll
    for (int f = 0; f < 8; ++f)
        #pragma unroll
        for (int d2 = 0; d2 < 4; ++d2) {
            v2 t; t.x = Fm[(2 * d2) * 8 + f]; t.y = Fm[(2 * d2 + 1) * 8 + f];
            Fcol2[f][d2] = t;
        }
    v2 Frowj[4];                        // row j of F, pairs over columns
    #pragma unroll
    for (int d2 = 0; d2 < 4; ++d2) {
        v2 t; t.x = Fm[j * 8 + 2 * d2]; t.y = Fm[j * 8 + 2 * d2 + 1];
        Frowj[d2] = t;
    }
    v2 Hrow2[2][4];
    #pragma unroll
    for (int m = 0; m < 2; ++m)
        #pragma unroll
        for (int d2 = 0; d2 < 4; ++d2) {
            v2 t; t.x = Hm[m * 8 + 2 * d2]; t.y = Hm[m * 8 + 2 * d2 + 1];
            Hrow2[m][d2] = t;
        }
    v2 HFrow2[2][4];                    // HF = H @ F
    #pragma unroll
    for (int m = 0; m < 2; ++m)
        #pragma unroll
        for (int d2 = 0; d2 < 4; ++d2) {
            float a = 0.f, c = 0.f;
            #pragma unroll
            for (int k = 0; k < 8; ++k) {
                a += Hm[m * 8 + k] * Fm[k * 8 + 2 * d2];
                c += Hm[m * 8 + k] * Fm[k * 8 + 2 * d2 + 1];
            }
            v2 t; t.x = a; t.y = c; HFrow2[m][d2] = t;
        }
    v2 Qrow2[4];
    #pragma unroll
    for (int e2 = 0; e2 < 4; ++e2) {
        v2 t; t.x = Qm[j * 8 + 2 * e2]; t.y = Qm[j * 8 + 2 * e2 + 1];
        Qrow2[e2] = t;
    }
    const float r00 = Rm[0], r01 = Rm[1], r10 = Rm[2], r11 = Rm[3];
    const float Rval = (j == 0) ? r00 : (j == 1) ? r01 : (j == 2) ? r10 : r11;
    v2 Hflat; Hflat.x = Hm[2 * j]; Hflat.y = Hm[2 * j + 1];   // Hs output chunk

    // ---- state: row j of P (symmetric, so row == column), mean[j] ----
    v2 P2[4];
    {
        const v4* c4 = (const v4*)(cov0 + (size_t)b * 64 + j * 8);
        v4 a = c4[0], bb = c4[1];
        P2[0].x = a.x;  P2[0].y = a.y;  P2[1].x = a.z;  P2[1].y = a.w;
        P2[2].x = bb.x; P2[2].y = bb.y; P2[3].x = bb.z; P2[3].y = bb.w;
    }
    float mean_j = mean0[(size_t)b * 8 + j];

    // initial hm = H @ mean  (gather mean through LDS, intra-wave)
    float hm0, hm1;
    mean_s[g * 12 + j] = mean_j;
    {
        const v4* ms = (const v4*)(mean_s + g * 12);
        v4 a = ms[0], bb = ms[1];
        v2 mu[4];
        mu[0].x = a.x;  mu[0].y = a.y;  mu[1].x = a.z;  mu[1].y = a.w;
        mu[2].x = bb.x; mu[2].y = bb.y; mu[3].x = bb.z; mu[3].y = bb.w;
        v2 t0 = {0.f, 0.f}, t1 = {0.f, 0.f};
        #pragma unroll
        for (int d2 = 0; d2 < 4; ++d2) { t0 += Hrow2[0][d2] * mu[d2]; t1 += Hrow2[1][d2] * mu[d2]; }
        hm0 = t0.x + t0.y; hm1 = t1.x + t1.y;
    }

    // ---- output pointers ----
    float* means_p = out + (size_t)b * T_STEPS * 8 + j;
    float* covs_p  = out + OFF_COVS + (size_t)b * T_STEPS * 64 + j * 8;
    float* Rs_p    = out + OFF_RS + (size_t)b * T_STEPS * 4 + j;    // j < 4 only
    float* Hs_p    = out + OFF_HS + (size_t)b * T_STEPS * 16 + 2 * j;
    const v2* xv   = (const v2*)(xs + g * 1024);

    v2 xcur = xv[0];

    for (int t = 0; t < T_STEPS; ++t) {
        // ---- hp[m] = HP[m,j] = H_row_m . P_row_j (local via symmetry) ----
        v2 a0 = {0.f, 0.f}, a1 = {0.f, 0.f};
        #pragma unroll
        for (int d2 = 0; d2 < 4; ++d2) { a0 += Hrow2[0][d2] * P2[d2]; a1 += Hrow2[1][d2] * P2[d2]; }
        const float hp0 = a0.x + a0.y;
        const float hp1 = a1.x + a1.y;
        hps[g * 28 + j]      = hp0;
        hps[g * 28 + 10 + j] = hp1;

        // ---- W = F*P, column j (local: col j of P == row j). 32 pk-FMA,
        //      K-independent -> hides the hp-gather round trip. ----
        v2 W2[4] = {{0.f,0.f},{0.f,0.f},{0.f,0.f},{0.f,0.f}};
        #pragma unroll
        for (int f = 0; f < 8; ++f) {
            const float pf = (f & 1) ? P2[f >> 1].y : P2[f >> 1].x;
            const v2 c = sp(pf);
            #pragma unroll
            for (int d2 = 0; d2 < 4; ++d2) W2[d2] += Fcol2[f][d2] * c;
        }
        #pragma unroll
        for (int d = 0; d < 8; ++d) {
            const float wd = (d & 1) ? W2[d >> 1].y : W2[d >> 1].x;
            ws[g * 84 + d * 10 + j] = wd;
        }

        // ---- emit prior state (independent global stores, fire & forget) ----
        means_p[0] = mean_j;
        {
            v4 cva, cvb;
            cva.x = P2[0].x; cva.y = P2[0].y; cva.z = P2[1].x; cva.w = P2[1].y;
            cvb.x = P2[2].x; cvb.y = P2[2].y; cvb.z = P2[3].x; cvb.w = P2[3].y;
            ((v4*)covs_p)[0] = cva;
            ((v4*)covs_p)[1] = cvb;
        }
        if (j < 4) Rs_p[0] = Rval;
        *((v2*)Hs_p) = Hflat;
        means_p += 8; covs_p += 64; Rs_p += 4; Hs_p += 16;

        // ---- prefetch next x ----
        const v2 xnext = xv[(t + 1) & (T_STEPS - 1)];

        // ---- gather full HP rows ----
        v2 hpa0[4], hpa1[4];
        {
            const v2* p0 = (const v2*)(hps + g * 28);
            const v2* p1 = (const v2*)(hps + g * 28 + 10);
            #pragma unroll
            for (int f2 = 0; f2 < 4; ++f2) { hpa0[f2] = p0[f2]; hpa1[f2] = p1[f2]; }
        }

        // ---- S = HP H^T + R (2x2), closed-form inverse ----
        v2 s00v = {0.f, 0.f}, s01v = {0.f, 0.f}, s11v = {0.f, 0.f};
        #pragma unroll
        for (int f2 = 0; f2 < 4; ++f2) {
            s00v += hpa0[f2] * Hrow2[0][f2];
            s01v += hpa0[f2] * Hrow2[1][f2];
            s11v += hpa1[f2] * Hrow2[1][f2];
        }
        const float s00 = s00v.x + s00v.y + r00;
        const float s01 = s01v.x + s01v.y + r01;
        const float s11 = s11v.x + s11v.y + r11;
        const float det = s00 * s11 - s01 * s01;
        const float idet = __builtin_amdgcn_rcpf(det);
        const float i00 = s11 * idet, i01 = -s01 * idet, i11 = s00 * idet;

        // ---- own gain, residual, mean update; scatter mean_u early ----
        const float kt0 = i00 * hp0 + i01 * hp1;
        const float kt1 = i01 * hp0 + i11 * hp1;
        const float rs0 = xcur.x - hm0;
        const float rs1 = xcur.y - hm1;
        const float mean_u = mean_j + kt0 * rs0 + kt1 * rs1;
        mean_s[g * 12 + j] = mean_u;

        // ---- rank-2 correction, row j:  corr = z . F^T,
        //      z[l] = c0*HP[0,l] + c1*HP[1,l],
        //      c_m  = iS[m,0]*(Frowj.hp0) + iS[m,1]*(Frowj.hp1) ----
        v2 dd0 = {0.f, 0.f}, dd1 = {0.f, 0.f};
        #pragma unroll
        for (int f2 = 0; f2 < 4; ++f2) { dd0 += Frowj[f2] * hpa0[f2]; dd1 += Frowj[f2] * hpa1[f2]; }
        const float d0 = dd0.x + dd0.y;
        const float d1 = dd1.x + dd1.y;
        const float c0 = i00 * d0 + i01 * d1;
        const float c1 = i01 * d0 + i11 * d1;
        const v2 c0v = sp(c0), c1v = sp(c1);
        v2 z[4];
        #pragma unroll
        for (int f2 = 0; f2 < 4; ++f2) z[f2] = c0v * hpa0[f2] + c1v * hpa1[f2];

        // ---- read W row j (transpose gather) + full mean_u ----
        v2 Wr[4];
        {
            const v2* wp = (const v2*)(ws + g * 84 + j * 10);
            #pragma unroll
            for (int f2 = 0; f2 < 4; ++f2) Wr[f2] = wp[f2];
        }
        v2 mu2[4];
        {
            const v4* ms = (const v4*)(mean_s + g * 12);
            v4 a = ms[0], bb = ms[1];
            mu2[0].x = a.x;  mu2[0].y = a.y;  mu2[1].x = a.z;  mu2[1].y = a.w;
            mu2[2].x = bb.x; mu2[2].y = bb.y; mu2[3].x = bb.z; mu2[3].y = bb.w;
        }

        // ---- cov_p row j = (Wrow - z) . F^T + Q ----
        v2 Wt[4];
        #pragma unroll
        for (int f2 = 0; f2 < 4; ++f2) Wt[f2] = Wr[f2] - z[f2];
        v2 Pn[4] = {Qrow2[0], Qrow2[1], Qrow2[2], Qrow2[3]};
        #pragma unroll
        for (int f = 0; f < 8; ++f) {
            const float wtf = (f & 1) ? Wt[f >> 1].y : Wt[f >> 1].x;
            const v2 c = sp(wtf);
            #pragma unroll
            for (int e2 = 0; e2 < 4; ++e2) Pn[e2] += Fcol2[f][e2] * c;
        }
        P2[0] = Pn[0]; P2[1] = Pn[1]; P2[2] = Pn[2]; P2[3] = Pn[3];

        // ---- mean predict: mean_j = F[j,:].mean_u ; hm = (H F).mean_u ----
        v2 t0 = {0.f, 0.f}, t1 = {0.f, 0.f}, t2 = {0.f, 0.f};
        #pragma unroll
        for (int d2 = 0; d2 < 4; ++d2) {
            t0 += Frowj[d2] * mu2[d2];
            t1 += HFrow2[0][d2] * mu2[d2];
            t2 += HFrow2[1][d2] * mu2[d2];
        }
        mean_j = t0.x + t0.y;
        hm0 = t1.x + t1.y;
        hm1 = t2.x + t2.y;
        xcur = xnext;
    }
}

extern "C" void kernel_launch(void* const* d_in, const int* in_sizes, int n_in,
                              void* d_out, int out_size, void* d_ws, size_t ws_size,
                              hipStream_t stream) {
    const float* input = (const float*)d_in[0];
    const float* mean0 = (const float*)d_in[1];
    const float* cov0  = (const float*)d_in[2];
    const float* F     = (const float*)d_in[3];
    const float* H     = (const float*)d_in[4];
    const float* Q     = (const float*)d_in[5];
    const float* R     = (const float*)d_in[6];
    float* out = (float*)d_out;

    hipLaunchKernelGGL(kf_kernel, dim3(B_TOT / 8), dim3(64), 0, stream,
                       input, mean0, cov0, F, H, Q, R, out);
}